// Round 1
// baseline (649.185 us; speedup 1.0000x reference)
//
#include <hip/hip_runtime.h>
#include <hip/hip_bf16.h>
#include <math.h>

// Problem constants (match reference)
constexpr int B_  = 2;
constexpr int Q_  = 2048;
constexpr int D_  = 1024;
constexpr int H_  = 16;
constexpr int R_  = 12;
constexpr int DH_ = 64;
constexpr int M_  = B_ * Q_;         // 4096 rows
constexpr int HR_ = H_ * R_;         // 192

// ---------------------------------------------------------------------------
// Generic fp32 GEMM: C[m,n] = sum_k A[m,k] * W[n,k] + bias[n]
// A: M x K row-major, W: N x K row-major (i.e. computing A @ W^T + bias)
// 64x64 tile, BK=16, 256 threads, 4x4 accum per thread.
// LDS stored transposed [k][row] with pad to 68 -> 2-way conflicts max.
// ---------------------------------------------------------------------------
__global__ __launch_bounds__(256) void gemm_nt(const float* __restrict__ A,
                                               const float* __restrict__ W,
                                               const float* __restrict__ bias,
                                               float* __restrict__ C,
                                               int M, int N, int K) {
    __shared__ float As[16][68];
    __shared__ float Bs[16][68];
    const int tid  = threadIdx.x;
    const int bm   = blockIdx.y * 64;
    const int bn   = blockIdx.x * 64;
    const int lrow = tid >> 2;          // 0..63
    const int lk   = (tid & 3) << 2;    // 0,4,8,12
    const float* Ap = A + (size_t)(bm + lrow) * K + lk;
    const float* Wp = W + (size_t)(bn + lrow) * K + lk;
    const int tx = tid & 15;            // 0..15 -> col group
    const int ty = tid >> 4;            // 0..15 -> row group

    float acc[4][4] = {};

    for (int k0 = 0; k0 < K; k0 += 16) {
        const float4 av = *(const float4*)(Ap + k0);
        const float4 bv = *(const float4*)(Wp + k0);
        __syncthreads();   // protect previous iteration's reads
        As[lk + 0][lrow] = av.x;
        As[lk + 1][lrow] = av.y;
        As[lk + 2][lrow] = av.z;
        As[lk + 3][lrow] = av.w;
        Bs[lk + 0][lrow] = bv.x;
        Bs[lk + 1][lrow] = bv.y;
        Bs[lk + 2][lrow] = bv.z;
        Bs[lk + 3][lrow] = bv.w;
        __syncthreads();
        #pragma unroll
        for (int kk = 0; kk < 16; ++kk) {
            const float4 a = *(const float4*)&As[kk][ty << 2];
            const float4 b = *(const float4*)&Bs[kk][tx << 2];
            const float a4[4] = {a.x, a.y, a.z, a.w};
            const float b4[4] = {b.x, b.y, b.z, b.w};
            #pragma unroll
            for (int i = 0; i < 4; ++i)
                #pragma unroll
                for (int j = 0; j < 4; ++j)
                    acc[i][j] = fmaf(a4[i], b4[j], acc[i][j]);
        }
    }

    const int colBase = bn + (tx << 2);
    const float4 bb = *(const float4*)&bias[colBase];
    const float bias4[4] = {bb.x, bb.y, bb.z, bb.w};
    #pragma unroll
    for (int i = 0; i < 4; ++i) {
        const int row = bm + (ty << 2) + i;
        float4 o;
        o.x = acc[i][0] + bias4[0];
        o.y = acc[i][1] + bias4[1];
        o.z = acc[i][2] + bias4[2];
        o.w = acc[i][3] + bias4[3];
        *(float4*)&C[(size_t)row * N + colBase] = o;
    }
}

// ---------------------------------------------------------------------------
// Depthwise conv1d (k=3, zero pad) over t + bias + exact GELU.
// Input q_lin as (b*t, c); output g as (b*t, c).
// One thread handles 4 consecutive channels of one row.
// ---------------------------------------------------------------------------
__global__ __launch_bounds__(256) void dwgelu_kernel(const float* __restrict__ qb,
                                                     const float* __restrict__ dww,
                                                     const float* __restrict__ dwb,
                                                     float* __restrict__ g) {
    const int idx = blockIdx.x * 256 + threadIdx.x;   // over M_*D_/4
    const int m   = idx >> 8;                         // D_/4 = 256 groups per row
    const int c4  = (idx & 255) << 2;
    const int t   = m & (Q_ - 1);
    const float* row = qb + (size_t)m * D_ + c4;

    const float4 cur = *(const float4*)row;
    float4 prv = make_float4(0.f, 0.f, 0.f, 0.f);
    float4 nxt = make_float4(0.f, 0.f, 0.f, 0.f);
    if (t > 0)      prv = *(const float4*)(row - D_);
    if (t < Q_ - 1) nxt = *(const float4*)(row + D_);

    const float pv[4] = {prv.x, prv.y, prv.z, prv.w};
    const float cu[4] = {cur.x, cur.y, cur.z, cur.w};
    const float nx[4] = {nxt.x, nxt.y, nxt.z, nxt.w};
    float out[4];
    #pragma unroll
    for (int j = 0; j < 4; ++j) {
        const int c = c4 + j;
        const float w0 = dww[c * 3 + 0];
        const float w1 = dww[c * 3 + 1];
        const float w2 = dww[c * 3 + 2];
        const float v  = pv[j] * w0 + cu[j] * w1 + nx[j] * w2 + dwb[c];
        out[j] = 0.5f * v * (1.0f + erff(v * 0.70710678118654752f));
    }
    float4 o = make_float4(out[0], out[1], out[2], out[3]);
    *(float4*)&g[(size_t)m * D_ + c4] = o;
}

// ---------------------------------------------------------------------------
// Sparse offset-guided attention.
// One 64-lane wave per (b,h,t); lane = dh. 4 waves per block.
// ---------------------------------------------------------------------------
__global__ __launch_bounds__(256) void attn_kernel(const float* __restrict__ qb,
                                                   const float* __restrict__ kb,
                                                   const float* __restrict__ vb,
                                                   const float* __restrict__ offb,
                                                   const float* __restrict__ rel_scale_p,
                                                   float* __restrict__ attb) {
    const int wid  = blockIdx.x * 4 + (threadIdx.x >> 6);
    const int lane = threadIdx.x & 63;
    const int t = wid & (Q_ - 1);
    const int h = (wid >> 11) & (H_ - 1);
    const int b = wid >> 15;
    const size_t mrow  = (size_t)b * Q_ + t;
    const size_t baseBH = (size_t)b * Q_ * D_ + h * DH_ + lane;

    const float qv = qb[mrow * D_ + h * DH_ + lane];
    const float rel_scale = rel_scale_p[0];

    float sc[R_], fr[R_];
    int   lo[R_], hi[R_];

    #pragma unroll
    for (int r = 0; r < R_; ++r) {
        const float off    = offb[mrow * HR_ + h * R_ + r];
        const float anchor = -2.0f + (4.0f / 11.0f) * (float)r;
        float pos = (float)t + anchor + 6.0f * tanhf(off);
        pos = fminf(fmaxf(pos, 0.0f), (float)(Q_ - 1));
        const float fl = floorf(pos);
        const int   l  = (int)fl;
        const int   hh = (int)ceilf(pos);
        const float f  = pos - fl;
        lo[r] = l; hi[r] = hh; fr[r] = f;

        const float klo = kb[baseBH + (size_t)l  * D_];
        const float khi = kb[baseBH + (size_t)hh * D_];
        const float sk  = klo * (1.0f - f) + khi * f;
        float p = qv * sk;
        #pragma unroll
        for (int o2 = 32; o2 > 0; o2 >>= 1) p += __shfl_xor(p, o2);
        sc[r] = p * 0.125f - rel_scale * fabsf(pos - (float)t);
    }

    float mx = sc[0];
    #pragma unroll
    for (int r = 1; r < R_; ++r) mx = fmaxf(mx, sc[r]);
    float sum = 0.0f;
    #pragma unroll
    for (int r = 0; r < R_; ++r) { sc[r] = expf(sc[r] - mx); sum += sc[r]; }
    const float inv = 1.0f / sum;

    float acc = 0.0f;
    #pragma unroll
    for (int r = 0; r < R_; ++r) {
        const float vlo = vb[baseBH + (size_t)lo[r] * D_];
        const float vhi = vb[baseBH + (size_t)hi[r] * D_];
        const float sv  = vlo * (1.0f - fr[r]) + vhi * fr[r];
        acc += sc[r] * inv * sv;
    }
    attb[mrow * D_ + h * DH_ + lane] = acc;
}

// ---------------------------------------------------------------------------
// Launch
// ---------------------------------------------------------------------------
extern "C" void kernel_launch(void* const* d_in, const int* in_sizes, int n_in,
                              void* d_out, int out_size, void* d_ws, size_t ws_size,
                              hipStream_t stream) {
    const float* x    = (const float*)d_in[0];
    const float* wq   = (const float*)d_in[1];
    const float* bq   = (const float*)d_in[2];
    const float* wk   = (const float*)d_in[3];
    const float* bk   = (const float*)d_in[4];
    const float* wv   = (const float*)d_in[5];
    const float* bv   = (const float*)d_in[6];
    const float* wo   = (const float*)d_in[7];
    const float* bo   = (const float*)d_in[8];
    const float* dww  = (const float*)d_in[9];
    const float* dwb  = (const float*)d_in[10];
    const float* pww  = (const float*)d_in[11];
    const float* pwb  = (const float*)d_in[12];
    const float* rsc  = (const float*)d_in[13];
    float* out = (float*)d_out;

    float* qbuf = (float*)d_ws;                 // M_*D_
    float* kbuf = qbuf + (size_t)M_ * D_;       // M_*D_
    float* vbuf = kbuf + (size_t)M_ * D_;       // M_*D_
    float* offb = vbuf + (size_t)M_ * D_;       // M_*HR_
    float* gbuf = offb + (size_t)M_ * HR_;      // M_*D_
    float* attb = gbuf;                          // reuse g region after offsets

    dim3 blk(256);
    // QKV projections
    dim3 gQKV(D_ / 64, M_ / 64);
    hipLaunchKernelGGL(gemm_nt, gQKV, blk, 0, stream, x, wq, bq, qbuf, M_, D_, D_);
    hipLaunchKernelGGL(gemm_nt, gQKV, blk, 0, stream, x, wk, bk, kbuf, M_, D_, D_);
    hipLaunchKernelGGL(gemm_nt, gQKV, blk, 0, stream, x, wv, bv, vbuf, M_, D_, D_);

    // depthwise conv + gelu
    dim3 gDW((M_ * D_ / 4) / 256);
    hipLaunchKernelGGL(dwgelu_kernel, gDW, blk, 0, stream, qbuf, dww, dwb, gbuf);

    // pointwise conv -> raw offsets (tanh applied in attention kernel)
    dim3 gPW(HR_ / 64, M_ / 64);
    hipLaunchKernelGGL(gemm_nt, gPW, blk, 0, stream, gbuf, pww, pwb, offb, M_, HR_, D_);

    // attention
    dim3 gAT((B_ * H_ * Q_) / 4);
    hipLaunchKernelGGL(attn_kernel, gAT, blk, 0, stream, qbuf, kbuf, vbuf, offb, rsc, attb);

    // output projection
    dim3 gO(D_ / 64, M_ / 64);
    hipLaunchKernelGGL(gemm_nt, gO, blk, 0, stream, attb, wo, bo, out, M_, D_, D_);
}

// Round 2
// 227.577 us; speedup vs baseline: 2.8526x; 2.8526x over previous
//
#include <hip/hip_runtime.h>
#include <math.h>

// Problem constants
constexpr int B_  = 2;
constexpr int Q_  = 2048;
constexpr int D_  = 1024;
constexpr int H_  = 16;
constexpr int R_  = 12;
constexpr int DH_ = 64;
constexpr int M_  = B_ * Q_;     // 4096
constexpr int HR_ = H_ * R_;     // 192
constexpr int NQKV = 3 * D_;     // 3072

typedef short bf16x8 __attribute__((ext_vector_type(8)));
typedef float f32x4  __attribute__((ext_vector_type(4)));

__device__ __forceinline__ float bf2f(unsigned short u) {
    return __uint_as_float(((unsigned)u) << 16);
}
__device__ __forceinline__ unsigned short f2bf(float f) {
    unsigned u = __float_as_uint(f);
    return (unsigned short)((u + 0x7fffu + ((u >> 16) & 1u)) >> 16);
}

// ---------------------------------------------------------------------------
// fp32 -> bf16 conversion, 8 elems/thread
// ---------------------------------------------------------------------------
__global__ __launch_bounds__(256) void cvt_kernel(const float* __restrict__ src,
                                                  unsigned short* __restrict__ dst,
                                                  int n8) {
    const int i = blockIdx.x * 256 + threadIdx.x;
    if (i >= n8) return;
    const float4 a = ((const float4*)src)[2 * i];
    const float4 b = ((const float4*)src)[2 * i + 1];
    uint4 o;
    o.x = (unsigned)f2bf(a.x) | ((unsigned)f2bf(a.y) << 16);
    o.y = (unsigned)f2bf(a.z) | ((unsigned)f2bf(a.w) << 16);
    o.z = (unsigned)f2bf(b.x) | ((unsigned)f2bf(b.y) << 16);
    o.w = (unsigned)f2bf(b.z) | ((unsigned)f2bf(b.w) << 16);
    ((uint4*)dst)[i] = o;
}

__global__ __launch_bounds__(256) void concat_bias(const float* __restrict__ bq,
                                                   const float* __restrict__ bk,
                                                   const float* __restrict__ bv,
                                                   float* __restrict__ dst) {
    const int i = blockIdx.x * 256 + threadIdx.x;  // 3072
    if (i >= NQKV) return;
    dst[i] = i < D_ ? bq[i] : (i < 2 * D_ ? bk[i - D_] : bv[i - 2 * D_]);
}

// ---------------------------------------------------------------------------
// bf16 MFMA GEMM (m97 structure): C[m,n] = A[m,:] . W[n,:] + bias[n]
// A: M x K bf16 row-major, W: N x K bf16 row-major.
// BM=128, BK=32, 256 threads = 4 waves (2x2), wave tile 64 x BN/2.
// global_load_lds width-16 staging, linear LDS, 2 barriers per K-step.
// ---------------------------------------------------------------------------
template <int BN, bool OUT_BF16>
__global__ __launch_bounds__(256) void gemm_mfma(const unsigned short* __restrict__ A,
                                                 const unsigned short* __restrict__ W,
                                                 const float* __restrict__ bias,
                                                 void* __restrict__ Cv,
                                                 int M, int N, int K) {
    constexpr int BM  = 128, BK = 32;
    constexpr int FN  = BN / 32;              // frags per wave along n
    constexpr int CHA = BM * BK * 2 / 1024;   // 1KB staging chunks for A (8)
    constexpr int CHB = BN * BK * 2 / 1024;   // for B (8 or 4)
    __shared__ unsigned short As[BM * BK];
    __shared__ unsigned short Bs[BN * BK];

    const int tid  = threadIdx.x;
    const int w    = tid >> 6, lane = tid & 63;
    const int wm   = w >> 1,   wn   = w & 1;
    const int bm   = blockIdx.y * BM, bn = blockIdx.x * BN;
    const int lrow = lane >> 2;            // 0..15 within 16-row chunk
    const int lcol = (lane & 3) << 3;      // 0,8,16,24 elem offset
    const int fr   = lane & 15;            // fragment row/col
    const int fo   = (lane >> 4) << 3;     // fragment k elem offset

    f32x4 acc[4][FN];
    #pragma unroll
    for (int i = 0; i < 4; ++i)
        #pragma unroll
        for (int j = 0; j < FN; ++j) acc[i][j] = (f32x4){0.f, 0.f, 0.f, 0.f};

    for (int k0 = 0; k0 < K; k0 += BK) {
        __syncthreads();   // previous iter's LDS reads complete before overwrite
        #pragma unroll
        for (int c = w; c < CHA; c += 4) {
            const unsigned short* g = A + (size_t)(bm + c * 16 + lrow) * K + k0 + lcol;
            __builtin_amdgcn_global_load_lds(
                (const __attribute__((address_space(1))) void*)g,
                (__attribute__((address_space(3))) void*)((char*)As + c * 1024), 16, 0, 0);
        }
        #pragma unroll
        for (int c = w; c < CHB; c += 4) {
            const unsigned short* g = W + (size_t)(bn + c * 16 + lrow) * K + k0 + lcol;
            __builtin_amdgcn_global_load_lds(
                (const __attribute__((address_space(1))) void*)g,
                (__attribute__((address_space(3))) void*)((char*)Bs + c * 1024), 16, 0, 0);
        }
        __syncthreads();   // waits vmcnt(0): staged data visible

        bf16x8 af[4];
        #pragma unroll
        for (int i = 0; i < 4; ++i)
            af[i] = *(const bf16x8*)(As + (wm * 64 + i * 16 + fr) * BK + fo);
        #pragma unroll
        for (int j = 0; j < FN; ++j) {
            const bf16x8 bfrag = *(const bf16x8*)(Bs + (wn * (BN / 2) + j * 16 + fr) * BK + fo);
            #pragma unroll
            for (int i = 0; i < 4; ++i)
                acc[i][j] = __builtin_amdgcn_mfma_f32_16x16x32_bf16(af[i], bfrag, acc[i][j], 0, 0, 0);
        }
    }

    // Epilogue: C/D layout col=lane&15, row=(lane>>4)*4+reg (m89-verified)
    #pragma unroll
    for (int j = 0; j < FN; ++j) {
        const int col = bn + wn * (BN / 2) + j * 16 + fr;
        const float bv = bias[col];
        #pragma unroll
        for (int i = 0; i < 4; ++i) {
            const int row0 = bm + wm * 64 + i * 16 + ((lane >> 4) << 2);
            #pragma unroll
            for (int ii = 0; ii < 4; ++ii) {
                const float v = acc[i][j][ii] + bv;
                if constexpr (OUT_BF16)
                    ((unsigned short*)Cv)[(size_t)(row0 + ii) * N + col] = f2bf(v);
                else
                    ((float*)Cv)[(size_t)(row0 + ii) * N + col] = v;
            }
        }
    }
}

// ---------------------------------------------------------------------------
// Depthwise conv1d (k=3) + bias + exact GELU. Reads q cols of fused qkv buf.
// 8 channels per thread.
// ---------------------------------------------------------------------------
__global__ __launch_bounds__(256) void dwgelu_kernel(const unsigned short* __restrict__ qkv,
                                                     const float* __restrict__ dww,
                                                     const float* __restrict__ dwb,
                                                     unsigned short* __restrict__ g) {
    const int idx = blockIdx.x * 256 + threadIdx.x;   // over M_ * 128
    const int m   = idx >> 7;
    const int c8  = (idx & 127) << 3;
    const int t   = m & (Q_ - 1);
    const unsigned short* row = qkv + (size_t)m * NQKV + c8;

    unsigned short cur[8], prv[8] = {0}, nxt[8] = {0};
    *(uint4*)cur = *(const uint4*)row;
    if (t > 0)      *(uint4*)prv = *(const uint4*)(row - NQKV);
    if (t < Q_ - 1) *(uint4*)nxt = *(const uint4*)(row + NQKV);

    unsigned short o[8];
    #pragma unroll
    for (int j = 0; j < 8; ++j) {
        const int c = c8 + j;
        float v = bf2f(prv[j]) * dww[c * 3 + 0] + bf2f(cur[j]) * dww[c * 3 + 1]
                + bf2f(nxt[j]) * dww[c * 3 + 2] + dwb[c];
        v = 0.5f * v * (1.0f + erff(v * 0.70710678118654752f));
        o[j] = f2bf(v);
    }
    *(uint4*)(g + (size_t)m * D_ + c8) = *(uint4*)o;
}

// ---------------------------------------------------------------------------
// Offset-guided sparse attention. One wave per (b,h,t), lane = dh.
// ---------------------------------------------------------------------------
__global__ __launch_bounds__(256) void attn_kernel(const unsigned short* __restrict__ qkv,
                                                   const unsigned short* __restrict__ offb,
                                                   const float* __restrict__ rel_scale_p,
                                                   unsigned short* __restrict__ attb) {
    const int wid  = blockIdx.x * 4 + (threadIdx.x >> 6);
    const int lane = threadIdx.x & 63;
    const int t = wid & (Q_ - 1);
    const int h = (wid >> 11) & (H_ - 1);
    const int b = wid >> 15;
    const size_t mrow  = (size_t)b * Q_ + t;
    const size_t kbase = (size_t)b * Q_ * NQKV + D_ + h * DH_ + lane;      // K cols
    const size_t vbase = kbase + D_;                                       // V cols

    const float qv = bf2f(qkv[mrow * NQKV + h * DH_ + lane]);
    const float rel_scale = rel_scale_p[0];

    float sc[R_], fr[R_];
    int   lo[R_], hi[R_];

    #pragma unroll
    for (int r = 0; r < R_; ++r) {
        const float off    = bf2f(offb[mrow * HR_ + h * R_ + r]);
        const float anchor = -2.0f + (4.0f / 11.0f) * (float)r;
        float pos = (float)t + anchor + 6.0f * tanhf(off);
        pos = fminf(fmaxf(pos, 0.0f), (float)(Q_ - 1));
        const float fl = floorf(pos);
        const int   l  = (int)fl;
        const int   hh = (int)ceilf(pos);
        const float f  = pos - fl;
        lo[r] = l; hi[r] = hh; fr[r] = f;

        const float klo = bf2f(qkv[kbase + (size_t)l  * NQKV]);
        const float khi = bf2f(qkv[kbase + (size_t)hh * NQKV]);
        const float sk  = klo * (1.0f - f) + khi * f;
        float p = qv * sk;
        #pragma unroll
        for (int o2 = 32; o2 > 0; o2 >>= 1) p += __shfl_xor(p, o2);
        sc[r] = p * 0.125f - rel_scale * fabsf(pos - (float)t);
    }

    float mx = sc[0];
    #pragma unroll
    for (int r = 1; r < R_; ++r) mx = fmaxf(mx, sc[r]);
    float sum = 0.0f;
    #pragma unroll
    for (int r = 0; r < R_; ++r) { sc[r] = expf(sc[r] - mx); sum += sc[r]; }
    const float inv = 1.0f / sum;

    float acc = 0.0f;
    #pragma unroll
    for (int r = 0; r < R_; ++r) {
        const float vlo = bf2f(qkv[vbase + (size_t)lo[r] * NQKV]);
        const float vhi = bf2f(qkv[vbase + (size_t)hi[r] * NQKV]);
        acc += sc[r] * inv * (vlo * (1.0f - fr[r]) + vhi * fr[r]);
    }
    attb[mrow * D_ + h * DH_ + lane] = f2bf(acc);
}

// ---------------------------------------------------------------------------
// Launch
// ---------------------------------------------------------------------------
extern "C" void kernel_launch(void* const* d_in, const int* in_sizes, int n_in,
                              void* d_out, int out_size, void* d_ws, size_t ws_size,
                              hipStream_t stream) {
    const float* x    = (const float*)d_in[0];
    const float* wq   = (const float*)d_in[1];
    const float* bq   = (const float*)d_in[2];
    const float* wk   = (const float*)d_in[3];
    const float* bk   = (const float*)d_in[4];
    const float* wv   = (const float*)d_in[5];
    const float* bv   = (const float*)d_in[6];
    const float* wo   = (const float*)d_in[7];
    const float* bo   = (const float*)d_in[8];
    const float* dww  = (const float*)d_in[9];
    const float* dwb  = (const float*)d_in[10];
    const float* pww  = (const float*)d_in[11];
    const float* pwb  = (const float*)d_in[12];
    const float* rsc  = (const float*)d_in[13];
    float* out = (float*)d_out;

    unsigned short* xb   = (unsigned short*)d_ws;              // M_*D_
    unsigned short* wqkv = xb   + (size_t)M_ * D_;             // NQKV*D_
    unsigned short* wob  = wqkv + (size_t)NQKV * D_;           // D_*D_
    unsigned short* pwwb = wob  + (size_t)D_ * D_;             // HR_*D_
    unsigned short* qkv  = pwwb + (size_t)HR_ * D_;            // M_*NQKV
    unsigned short* gb   = qkv  + (size_t)M_ * NQKV;           // M_*D_
    unsigned short* offb = gb   + (size_t)M_ * D_;             // M_*HR_
    unsigned short* attb = offb + (size_t)M_ * HR_;            // M_*D_
    float*          bqkv = (float*)(attb + (size_t)M_ * D_);   // NQKV

    dim3 blk(256);

    // fp32 -> bf16 conversions
    hipLaunchKernelGGL(cvt_kernel, dim3((M_ * D_ / 8) / 256), blk, 0, stream, x,   xb,   M_ * D_ / 8);
    hipLaunchKernelGGL(cvt_kernel, dim3((D_ * D_ / 8) / 256), blk, 0, stream, wq,  wqkv,                     D_ * D_ / 8);
    hipLaunchKernelGGL(cvt_kernel, dim3((D_ * D_ / 8) / 256), blk, 0, stream, wk,  wqkv + (size_t)D_ * D_,   D_ * D_ / 8);
    hipLaunchKernelGGL(cvt_kernel, dim3((D_ * D_ / 8) / 256), blk, 0, stream, wv,  wqkv + (size_t)2 * D_ * D_, D_ * D_ / 8);
    hipLaunchKernelGGL(cvt_kernel, dim3((D_ * D_ / 8) / 256), blk, 0, stream, wo,  wob,  D_ * D_ / 8);
    hipLaunchKernelGGL(cvt_kernel, dim3((HR_ * D_ / 8) / 256), blk, 0, stream, pww, pwwb, HR_ * D_ / 8);
    hipLaunchKernelGGL(concat_bias, dim3(12), blk, 0, stream, bq, bk, bv, bqkv);

    // fused QKV projection: (4096 x 1024) @ (3072 x 1024)^T
    hipLaunchKernelGGL((gemm_mfma<128, true>), dim3(NQKV / 128, M_ / 128), blk, 0, stream,
                       xb, wqkv, bqkv, qkv, M_, NQKV, D_);

    // depthwise conv + gelu
    hipLaunchKernelGGL(dwgelu_kernel, dim3(M_ * 128 / 256), blk, 0, stream, qkv, dww, dwb, gb);

    // pointwise conv -> raw offsets
    hipLaunchKernelGGL((gemm_mfma<64, true>), dim3(HR_ / 64, M_ / 128), blk, 0, stream,
                       gb, pwwb, pwb, offb, M_, HR_, D_);

    // attention
    hipLaunchKernelGGL(attn_kernel, dim3(B_ * H_ * Q_ / 4), blk, 0, stream, qkv, offb, rsc, attb);

    // output projection -> fp32 d_out
    hipLaunchKernelGGL((gemm_mfma<64, false>), dim3(D_ / 64, M_ / 128), blk, 0, stream,
                       attb, wob, bo, out, M_, D_, D_);
}

// Round 3
// 138.940 us; speedup vs baseline: 4.6724x; 1.6380x over previous
//
#include <hip/hip_runtime.h>
#include <math.h>

// Problem constants
constexpr int B_  = 2;
constexpr int Q_  = 2048;
constexpr int D_  = 1024;
constexpr int H_  = 16;
constexpr int R_  = 12;
constexpr int DH_ = 64;
constexpr int M_  = B_ * Q_;     // 4096
constexpr int HR_ = H_ * R_;     // 192
constexpr int NQKV = 3 * D_;     // 3072

typedef short bf16x8 __attribute__((ext_vector_type(8)));
typedef float f32x4  __attribute__((ext_vector_type(4)));

__device__ __forceinline__ float bf2f(unsigned short u) {
    return __uint_as_float(((unsigned)u) << 16);
}
__device__ __forceinline__ unsigned short f2bf(float f) {
    unsigned u = __float_as_uint(f);
    return (unsigned short)((u + 0x7fffu + ((u >> 16) & 1u)) >> 16);
}

// ---------------------------------------------------------------------------
// fp32 -> bf16 conversion, 8 elems/thread
// ---------------------------------------------------------------------------
__global__ __launch_bounds__(256) void cvt_kernel(const float* __restrict__ src,
                                                  unsigned short* __restrict__ dst,
                                                  int n8) {
    const int i = blockIdx.x * 256 + threadIdx.x;
    if (i >= n8) return;
    const float4 a = ((const float4*)src)[2 * i];
    const float4 b = ((const float4*)src)[2 * i + 1];
    uint4 o;
    o.x = (unsigned)f2bf(a.x) | ((unsigned)f2bf(a.y) << 16);
    o.y = (unsigned)f2bf(a.z) | ((unsigned)f2bf(a.w) << 16);
    o.z = (unsigned)f2bf(b.x) | ((unsigned)f2bf(b.y) << 16);
    o.w = (unsigned)f2bf(b.z) | ((unsigned)f2bf(b.w) << 16);
    ((uint4*)dst)[i] = o;
}

// three equally-sized sources -> contiguous dst (wq|wk|wv)
__global__ __launch_bounds__(256) void cvt3_kernel(const float* __restrict__ s0,
                                                   const float* __restrict__ s1,
                                                   const float* __restrict__ s2,
                                                   unsigned short* __restrict__ dst,
                                                   int n8per) {
    const int i = blockIdx.x * 256 + threadIdx.x;
    if (i >= n8per) return;
    const int which = blockIdx.y;
    const float* src = which == 0 ? s0 : (which == 1 ? s1 : s2);
    unsigned short* d = dst + (size_t)which * n8per * 8;
    const float4 a = ((const float4*)src)[2 * i];
    const float4 b = ((const float4*)src)[2 * i + 1];
    uint4 o;
    o.x = (unsigned)f2bf(a.x) | ((unsigned)f2bf(a.y) << 16);
    o.y = (unsigned)f2bf(a.z) | ((unsigned)f2bf(a.w) << 16);
    o.z = (unsigned)f2bf(b.x) | ((unsigned)f2bf(b.y) << 16);
    o.w = (unsigned)f2bf(b.z) | ((unsigned)f2bf(b.w) << 16);
    ((uint4*)d)[i] = o;
}

__global__ __launch_bounds__(256) void concat_bias(const float* __restrict__ bq,
                                                   const float* __restrict__ bk,
                                                   const float* __restrict__ bv,
                                                   float* __restrict__ dst) {
    const int i = blockIdx.x * 256 + threadIdx.x;  // 3072
    if (i >= NQKV) return;
    dst[i] = i < D_ ? bq[i] : (i < 2 * D_ ? bk[i - D_] : bv[i - 2 * D_]);
}

// ---------------------------------------------------------------------------
// bf16 MFMA GEMM (m97 structure): C[m,n] = A[m,:] . W[n,:] + bias[n]
// ---------------------------------------------------------------------------
template <int BN, bool OUT_BF16>
__global__ __launch_bounds__(256) void gemm_mfma(const unsigned short* __restrict__ A,
                                                 const unsigned short* __restrict__ W,
                                                 const float* __restrict__ bias,
                                                 void* __restrict__ Cv,
                                                 int M, int N, int K) {
    constexpr int BM  = 128, BK = 32;
    constexpr int FN  = BN / 32;
    constexpr int CHA = BM * BK * 2 / 1024;
    constexpr int CHB = BN * BK * 2 / 1024;
    __shared__ unsigned short As[BM * BK];
    __shared__ unsigned short Bs[BN * BK];

    const int tid  = threadIdx.x;
    const int w    = tid >> 6, lane = tid & 63;
    const int wm   = w >> 1,   wn   = w & 1;
    const int bm   = blockIdx.y * BM, bn = blockIdx.x * BN;
    const int lrow = lane >> 2;
    const int lcol = (lane & 3) << 3;
    const int fr   = lane & 15;
    const int fo   = (lane >> 4) << 3;

    f32x4 acc[4][FN];
    #pragma unroll
    for (int i = 0; i < 4; ++i)
        #pragma unroll
        for (int j = 0; j < FN; ++j) acc[i][j] = (f32x4){0.f, 0.f, 0.f, 0.f};

    for (int k0 = 0; k0 < K; k0 += BK) {
        __syncthreads();
        #pragma unroll
        for (int c = w; c < CHA; c += 4) {
            const unsigned short* g = A + (size_t)(bm + c * 16 + lrow) * K + k0 + lcol;
            __builtin_amdgcn_global_load_lds(
                (const __attribute__((address_space(1))) void*)g,
                (__attribute__((address_space(3))) void*)((char*)As + c * 1024), 16, 0, 0);
        }
        #pragma unroll
        for (int c = w; c < CHB; c += 4) {
            const unsigned short* g = W + (size_t)(bn + c * 16 + lrow) * K + k0 + lcol;
            __builtin_amdgcn_global_load_lds(
                (const __attribute__((address_space(1))) void*)g,
                (__attribute__((address_space(3))) void*)((char*)Bs + c * 1024), 16, 0, 0);
        }
        __syncthreads();

        bf16x8 af[4];
        #pragma unroll
        for (int i = 0; i < 4; ++i)
            af[i] = *(const bf16x8*)(As + (wm * 64 + i * 16 + fr) * BK + fo);
        #pragma unroll
        for (int j = 0; j < FN; ++j) {
            const bf16x8 bfrag = *(const bf16x8*)(Bs + (wn * (BN / 2) + j * 16 + fr) * BK + fo);
            #pragma unroll
            for (int i = 0; i < 4; ++i)
                acc[i][j] = __builtin_amdgcn_mfma_f32_16x16x32_bf16(af[i], bfrag, acc[i][j], 0, 0, 0);
        }
    }

    #pragma unroll
    for (int j = 0; j < FN; ++j) {
        const int col = bn + wn * (BN / 2) + j * 16 + fr;
        const float bv = bias[col];
        #pragma unroll
        for (int i = 0; i < 4; ++i) {
            const int row0 = bm + wm * 64 + i * 16 + ((lane >> 4) << 2);
            #pragma unroll
            for (int ii = 0; ii < 4; ++ii) {
                const float v = acc[i][j][ii] + bv;
                if constexpr (OUT_BF16)
                    ((unsigned short*)Cv)[(size_t)(row0 + ii) * N + col] = f2bf(v);
                else
                    ((float*)Cv)[(size_t)(row0 + ii) * N + col] = v;
            }
        }
    }
}

// ---------------------------------------------------------------------------
// Depthwise conv1d (k=3) + bias + exact GELU.
// ---------------------------------------------------------------------------
__global__ __launch_bounds__(256) void dwgelu_kernel(const unsigned short* __restrict__ qkv,
                                                     const float* __restrict__ dww,
                                                     const float* __restrict__ dwb,
                                                     unsigned short* __restrict__ g) {
    const int idx = blockIdx.x * 256 + threadIdx.x;
    const int m   = idx >> 7;
    const int c8  = (idx & 127) << 3;
    const int t   = m & (Q_ - 1);
    const unsigned short* row = qkv + (size_t)m * NQKV + c8;

    unsigned short cur[8], prv[8] = {0}, nxt[8] = {0};
    *(uint4*)cur = *(const uint4*)row;
    if (t > 0)      *(uint4*)prv = *(const uint4*)(row - NQKV);
    if (t < Q_ - 1) *(uint4*)nxt = *(const uint4*)(row + NQKV);

    unsigned short o[8];
    #pragma unroll
    for (int j = 0; j < 8; ++j) {
        const int c = c8 + j;
        float v = bf2f(prv[j]) * dww[c * 3 + 0] + bf2f(cur[j]) * dww[c * 3 + 1]
                + bf2f(nxt[j]) * dww[c * 3 + 2] + dwb[c];
        v = 0.5f * v * (1.0f + erff(v * 0.70710678118654752f));
        o[j] = f2bf(v);
    }
    *(uint4*)(g + (size_t)m * D_ + c8) = *(uint4*)o;
}

// ---------------------------------------------------------------------------
// Fused banded-score + softmax + coefficient kernel.
// One wave per 16-row t-tile of one (b,h). pos in [t-8, t+8] always, so
// scores only need the 17-wide diagonal band of QK^T.
// Phase 1: S[16][32] band via 4 MFMA (A/B frags direct from global).
// Phase 2: 64 lanes = 16 t x 4 r-groups (3 r each): tanh/exp + 2-step shfl,
//          scatter w*(1-f)/w*f into c[16][32] via LDS atomicAdd.
// Phase 3: store c tile to global (f32).
// ---------------------------------------------------------------------------
__global__ __launch_bounds__(256) void coeff_kernel(const unsigned short* __restrict__ qkv,
                                                    const unsigned short* __restrict__ offb,
                                                    const float* __restrict__ rel_scale_p,
                                                    float* __restrict__ cbuf) {
    __shared__ __align__(16) float S[4][16][33];
    __shared__ __align__(16) float C[4][16][32];
    const int tid  = threadIdx.x;
    const int w    = tid >> 6, lane = tid & 63;
    const int tile = blockIdx.x * 4 + w;      // (b,h,t0/16)
    const int t0   = (tile & 127) << 4;
    const int h    = (tile >> 7) & 15;
    const int b    = tile >> 11;
    const int fr   = lane & 15;
    const int fo   = (lane >> 4) << 3;

    // ---- Phase 1: banded QK^T ----
    const unsigned short* qrow = qkv + (size_t)(b * Q_ + t0 + fr) * NQKV + h * DH_ + fo;
    const bf16x8 af0 = *(const bf16x8*)qrow;
    const bf16x8 af1 = *(const bf16x8*)(qrow + 32);

    f32x4 acc0 = (f32x4){0.f, 0.f, 0.f, 0.f};
    f32x4 acc1 = acc0;
    {
        int j = t0 - 8 + fr;                // col tile 0
        j = min(max(j, 0), Q_ - 1);
        const unsigned short* krow = qkv + (size_t)(b * Q_ + j) * NQKV + D_ + h * DH_ + fo;
        acc0 = __builtin_amdgcn_mfma_f32_16x16x32_bf16(af0, *(const bf16x8*)krow, acc0, 0, 0, 0);
        acc0 = __builtin_amdgcn_mfma_f32_16x16x32_bf16(af1, *(const bf16x8*)(krow + 32), acc0, 0, 0, 0);
    }
    {
        int j = t0 + 8 + fr;                // col tile 1
        j = min(max(j, 0), Q_ - 1);
        const unsigned short* krow = qkv + (size_t)(b * Q_ + j) * NQKV + D_ + h * DH_ + fo;
        acc1 = __builtin_amdgcn_mfma_f32_16x16x32_bf16(af0, *(const bf16x8*)krow, acc1, 0, 0, 0);
        acc1 = __builtin_amdgcn_mfma_f32_16x16x32_bf16(af1, *(const bf16x8*)(krow + 32), acc1, 0, 0, 0);
    }

    // write S band: D layout col=lane&15, row=(lane>>4)*4+reg
    const int row0 = (lane >> 4) << 2;
    #pragma unroll
    for (int ii = 0; ii < 4; ++ii) {
        S[w][row0 + ii][fr]      = acc0[ii];
        S[w][row0 + ii][16 + fr] = acc1[ii];
    }
    // zero C: each lane 8 slots
    {
        const int tr = lane >> 2, cg = (lane & 3) << 3;
        #pragma unroll
        for (int k = 0; k < 8; ++k) C[w][tr][cg + k] = 0.f;
    }
    __syncthreads();

    // ---- Phase 2: softmax + scatter ----
    const int tloc = lane & 15;
    const int rs   = lane >> 4;
    const int t    = t0 + tloc;
    const float rel_scale = rel_scale_p[0];
    const unsigned short* offrow = offb + (size_t)(b * Q_ + t) * HR_ + h * R_;

    float sc[3], fr3[3];
    int   cl[3], ch[3];
    #pragma unroll
    for (int i = 0; i < 3; ++i) {
        const int r = rs * 3 + i;
        const float off    = bf2f(offrow[r]);
        const float anchor = -2.0f + (4.0f / 11.0f) * (float)r;
        float pos = (float)t + anchor + 6.0f * tanhf(off);
        pos = fminf(fmaxf(pos, 0.0f), (float)(Q_ - 1));
        const float fl = floorf(pos);
        const int lo = (int)fl;
        const int hi = (int)ceilf(pos);
        const float f = pos - fl;
        cl[i] = lo - t0 + 8;
        ch[i] = hi - t0 + 8;
        fr3[i] = f;
        const float slo = S[w][tloc][cl[i]];
        const float shi = S[w][tloc][ch[i]];
        sc[i] = (slo * (1.0f - f) + shi * f) * 0.125f - rel_scale * fabsf(pos - (float)t);
    }

    float mx = fmaxf(fmaxf(sc[0], sc[1]), sc[2]);
    mx = fmaxf(mx, __shfl_xor(mx, 16));
    mx = fmaxf(mx, __shfl_xor(mx, 32));
    float e[3];
    #pragma unroll
    for (int i = 0; i < 3; ++i) e[i] = expf(sc[i] - mx);
    float sum = e[0] + e[1] + e[2];
    sum += __shfl_xor(sum, 16);
    sum += __shfl_xor(sum, 32);
    const float inv = 1.0f / sum;

    #pragma unroll
    for (int i = 0; i < 3; ++i) {
        const float wgt = e[i] * inv;
        atomicAdd(&C[w][tloc][cl[i]], wgt * (1.0f - fr3[i]));
        atomicAdd(&C[w][tloc][ch[i]], wgt * fr3[i]);
    }
    __syncthreads();

    // ---- Phase 3: store C tile ----
    const int tr = lane >> 2, cg = (lane & 3) << 3;
    const float4 v0 = *(const float4*)&C[w][tr][cg];
    const float4 v1 = *(const float4*)&C[w][tr][cg + 4];
    float* dst = cbuf + ((size_t)((b * H_ + h) * Q_ + t0 + tr)) * 32 + cg;
    *(float4*)dst       = v0;
    *(float4*)(dst + 4) = v1;
}

// ---------------------------------------------------------------------------
// Banded PV: out[t,dh] = sum_k c[t, tloc+k] * V[t-8+k, dh], k=0..16.
// One wave per (b,h,t), lane = dh.
// ---------------------------------------------------------------------------
__global__ __launch_bounds__(256) void pv_kernel(const unsigned short* __restrict__ qkv,
                                                 const float* __restrict__ cbuf,
                                                 unsigned short* __restrict__ attb) {
    const int wid  = blockIdx.x * 4 + (threadIdx.x >> 6);
    const int lane = threadIdx.x & 63;
    const int t = wid & (Q_ - 1);
    const int h = (wid >> 11) & (H_ - 1);
    const int b = wid >> 15;
    const int tloc = t & 15;
    const float* crow = cbuf + (size_t)wid * 32 + tloc;
    const unsigned short* vbase = qkv + (size_t)b * Q_ * NQKV + 2 * D_ + h * DH_ + lane;

    float acc = 0.f;
    #pragma unroll
    for (int k = 0; k < 17; ++k) {
        const int j = min(max(t - 8 + k, 0), Q_ - 1);
        const float v = bf2f(vbase[(size_t)j * NQKV]);
        acc = fmaf(crow[k], v, acc);
    }
    attb[(size_t)(b * Q_ + t) * D_ + h * DH_ + lane] = f2bf(acc);
}

// ---------------------------------------------------------------------------
// Launch
// ---------------------------------------------------------------------------
extern "C" void kernel_launch(void* const* d_in, const int* in_sizes, int n_in,
                              void* d_out, int out_size, void* d_ws, size_t ws_size,
                              hipStream_t stream) {
    const float* x    = (const float*)d_in[0];
    const float* wq   = (const float*)d_in[1];
    const float* bq   = (const float*)d_in[2];
    const float* wk   = (const float*)d_in[3];
    const float* bk   = (const float*)d_in[4];
    const float* wv   = (const float*)d_in[5];
    const float* bv   = (const float*)d_in[6];
    const float* wo   = (const float*)d_in[7];
    const float* bo   = (const float*)d_in[8];
    const float* dww  = (const float*)d_in[9];
    const float* dwb  = (const float*)d_in[10];
    const float* pww  = (const float*)d_in[11];
    const float* pwb  = (const float*)d_in[12];
    const float* rsc  = (const float*)d_in[13];
    float* out = (float*)d_out;

    unsigned short* xb   = (unsigned short*)d_ws;              // M_*D_
    unsigned short* wqkv = xb   + (size_t)M_ * D_;             // NQKV*D_
    unsigned short* wob  = wqkv + (size_t)NQKV * D_;           // D_*D_
    unsigned short* pwwb = wob  + (size_t)D_ * D_;             // HR_*D_
    unsigned short* qkv  = pwwb + (size_t)HR_ * D_;            // M_*NQKV
    unsigned short* gb   = qkv  + (size_t)M_ * NQKV;           // M_*D_
    unsigned short* offb = gb   + (size_t)M_ * D_;             // M_*HR_
    unsigned short* attb = offb + (size_t)M_ * HR_;            // M_*D_
    float*          bqkv = (float*)(attb + (size_t)M_ * D_);   // NQKV
    float*          cbuf = bqkv + NQKV;                        // B_*H_*Q_*32

    dim3 blk(256);

    // fp32 -> bf16 conversions
    hipLaunchKernelGGL(cvt_kernel, dim3((M_ * D_ / 8) / 256), blk, 0, stream, x, xb, M_ * D_ / 8);
    hipLaunchKernelGGL(cvt3_kernel, dim3((D_ * D_ / 8) / 256, 3), blk, 0, stream,
                       wq, wk, wv, wqkv, D_ * D_ / 8);
    hipLaunchKernelGGL(cvt_kernel, dim3((D_ * D_ / 8) / 256), blk, 0, stream, wo, wob, D_ * D_ / 8);
    hipLaunchKernelGGL(cvt_kernel, dim3((HR_ * D_ / 8) / 256), blk, 0, stream, pww, pwwb, HR_ * D_ / 8);
    hipLaunchKernelGGL(concat_bias, dim3(12), blk, 0, stream, bq, bk, bv, bqkv);

    // fused QKV projection
    hipLaunchKernelGGL((gemm_mfma<128, true>), dim3(NQKV / 128, M_ / 128), blk, 0, stream,
                       xb, wqkv, bqkv, qkv, M_, NQKV, D_);

    // depthwise conv + gelu
    hipLaunchKernelGGL(dwgelu_kernel, dim3(M_ * 128 / 256), blk, 0, stream, qkv, dww, dwb, gb);

    // pointwise conv -> raw offsets
    hipLaunchKernelGGL((gemm_mfma<64, true>), dim3(HR_ / 64, M_ / 128), blk, 0, stream,
                       gb, pwwb, pwb, offb, M_, HR_, D_);

    // banded score + softmax + coefficients
    hipLaunchKernelGGL(coeff_kernel, dim3(B_ * H_ * (Q_ / 16) / 4), blk, 0, stream,
                       qkv, offb, rsc, cbuf);

    // banded PV
    hipLaunchKernelGGL(pv_kernel, dim3(B_ * H_ * Q_ / 4), blk, 0, stream, qkv, cbuf, attb);

    // output projection -> fp32 d_out
    hipLaunchKernelGGL((gemm_mfma<64, false>), dim3(D_ / 64, M_ / 128), blk, 0, stream,
                       attb, wob, bo, out, M_, D_, D_);
}

// Round 4
// 97.734 us; speedup vs baseline: 6.6423x; 1.4216x over previous
//
#include <hip/hip_runtime.h>
#include <math.h>

// Problem constants
constexpr int B_  = 2;
constexpr int Q_  = 2048;
constexpr int D_  = 1024;
constexpr int H_  = 16;
constexpr int R_  = 12;
constexpr int DH_ = 64;
constexpr int M_  = B_ * Q_;     // 4096
constexpr int HR_ = H_ * R_;     // 192
constexpr int NQKV = 3 * D_;     // 3072

typedef short bf16x8 __attribute__((ext_vector_type(8)));
typedef float f32x4  __attribute__((ext_vector_type(4)));

__device__ __forceinline__ float bf2f(unsigned short u) {
    return __uint_as_float(((unsigned)u) << 16);
}
__device__ __forceinline__ unsigned short f2bf(float f) {
    unsigned u = __float_as_uint(f);
    return (unsigned short)((u + 0x7fffu + ((u >> 16) & 1u)) >> 16);
}

// ---------------------------------------------------------------------------
// One merged conversion kernel: x|wq|wk|wv|wo|pww fp32->bf16 (+ bias concat).
// Segment boundaries are all multiples of 256 blocks, so no straddling.
// ---------------------------------------------------------------------------
__global__ __launch_bounds__(256) void cvt_all(const float* __restrict__ x,
                                               const float* __restrict__ wq,
                                               const float* __restrict__ wk,
                                               const float* __restrict__ wv,
                                               const float* __restrict__ wo,
                                               const float* __restrict__ pww,
                                               const float* __restrict__ bq,
                                               const float* __restrict__ bk,
                                               const float* __restrict__ bv,
                                               unsigned short* __restrict__ xb,
                                               unsigned short* __restrict__ wqkv,
                                               unsigned short* __restrict__ wob,
                                               unsigned short* __restrict__ pwwb,
                                               float* __restrict__ bqkv) {
    const int blk = blockIdx.x;
    if (blk >= 4192) {  // bias concat: 12 blocks x 256 = 3072
        const int i = (blk - 4192) * 256 + threadIdx.x;
        bqkv[i] = i < D_ ? bq[i] : (i < 2 * D_ ? bk[i - D_] : bv[i - 2 * D_]);
        return;
    }
    const int i = blk * 256 + threadIdx.x;  // 8-element unit index
    const float* src;
    unsigned short* dst;
    int rel;
    if (i < 524288)       { src = x;   dst = xb;                          rel = i; }
    else if (i < 655360)  { src = wq;  dst = wqkv;                        rel = i - 524288; }
    else if (i < 786432)  { src = wk;  dst = wqkv + (size_t)D_ * D_;      rel = i - 655360; }
    else if (i < 917504)  { src = wv;  dst = wqkv + (size_t)2 * D_ * D_;  rel = i - 786432; }
    else if (i < 1048576) { src = wo;  dst = wob;                         rel = i - 917504; }
    else                  { src = pww; dst = pwwb;                        rel = i - 1048576; }

    const float4 a = ((const float4*)src)[2 * rel];
    const float4 b = ((const float4*)src)[2 * rel + 1];
    uint4 o;
    o.x = (unsigned)f2bf(a.x) | ((unsigned)f2bf(a.y) << 16);
    o.y = (unsigned)f2bf(a.z) | ((unsigned)f2bf(a.w) << 16);
    o.z = (unsigned)f2bf(b.x) | ((unsigned)f2bf(b.y) << 16);
    o.w = (unsigned)f2bf(b.z) | ((unsigned)f2bf(b.w) << 16);
    ((uint4*)dst)[rel] = o;
}

// ---------------------------------------------------------------------------
// bf16 MFMA GEMM, BK=64, both-sides 16B-slot XOR swizzle, XCD block swizzle.
// C[m,n] = A[m,:] . W[n,:] + bias[n].  BM=128, 4 waves (2x2).
// LDS invariant: As[r][p] = A[bm+r][k0 + (p ^ (r&7))*8 ..] ; read applies same XOR.
// ---------------------------------------------------------------------------
template <int BN, bool OUT_BF16>
__global__ __launch_bounds__(256) void gemm_mfma(const unsigned short* __restrict__ A,
                                                 const unsigned short* __restrict__ W,
                                                 const float* __restrict__ bias,
                                                 void* __restrict__ Cv,
                                                 int M, int N, int K) {
    constexpr int BM  = 128, BK = 64;
    constexpr int FN  = BN / 32;
    constexpr int CHA = BM / 8;     // 1KB chunks (8 rows x 128B)
    constexpr int CHB = BN / 8;
    __shared__ unsigned short As[BM * BK];
    __shared__ unsigned short Bs[BN * BK];

    const int tid  = threadIdx.x;
    const int w    = tid >> 6, lane = tid & 63;
    const int wm   = w >> 1,   wn   = w & 1;

    // XCD-aware block swizzle (nwg % 8 == 0 for all our grids)
    const int nbx = gridDim.x;
    const int nwg = nbx * gridDim.y;
    int flat = blockIdx.y * nbx + blockIdx.x;
    flat = (flat & 7) * (nwg >> 3) + (flat >> 3);
    const int bm = (flat / nbx) * BM;
    const int bn = (flat % nbx) * BN;

    const int srow  = lane >> 3;                 // staging row within chunk
    const int sslot = (lane & 7) ^ (srow & 7);   // pre-swizzled global slot
    const int fr = lane & 15;
    const int s  = lane >> 4;                    // k sub-slot 0..3
    const int fx = fr & 7;                       // read-side xor

    f32x4 acc[4][FN];
    #pragma unroll
    for (int i = 0; i < 4; ++i)
        #pragma unroll
        for (int j = 0; j < FN; ++j) acc[i][j] = (f32x4){0.f, 0.f, 0.f, 0.f};

    for (int k0 = 0; k0 < K; k0 += BK) {
        __syncthreads();
        #pragma unroll
        for (int c = w; c < CHA; c += 4) {
            const unsigned short* g = A + (size_t)(bm + c * 8 + srow) * K + k0 + sslot * 8;
            __builtin_amdgcn_global_load_lds(
                (const __attribute__((address_space(1))) void*)g,
                (__attribute__((address_space(3))) void*)((char*)As + c * 1024), 16, 0, 0);
        }
        #pragma unroll
        for (int c = w; c < CHB; c += 4) {
            const unsigned short* g = W + (size_t)(bn + c * 8 + srow) * K + k0 + sslot * 8;
            __builtin_amdgcn_global_load_lds(
                (const __attribute__((address_space(1))) void*)g,
                (__attribute__((address_space(3))) void*)((char*)Bs + c * 1024), 16, 0, 0);
        }
        __syncthreads();

        #pragma unroll
        for (int ks = 0; ks < 2; ++ks) {
            const int sl = (((ks << 2) | s) ^ fx) * 8;
            bf16x8 af[4];
            #pragma unroll
            for (int i = 0; i < 4; ++i)
                af[i] = *(const bf16x8*)(As + (wm * 64 + i * 16 + fr) * BK + sl);
            #pragma unroll
            for (int j = 0; j < FN; ++j) {
                const bf16x8 bfrag = *(const bf16x8*)(Bs + (wn * (BN / 2) + j * 16 + fr) * BK + sl);
                #pragma unroll
                for (int i = 0; i < 4; ++i)
                    acc[i][j] = __builtin_amdgcn_mfma_f32_16x16x32_bf16(af[i], bfrag, acc[i][j], 0, 0, 0);
            }
        }
    }

    // Epilogue: C/D layout col=lane&15, row=(lane>>4)*4+reg
    #pragma unroll
    for (int j = 0; j < FN; ++j) {
        const int col = bn + wn * (BN / 2) + j * 16 + fr;
        const float bv = bias[col];
        #pragma unroll
        for (int i = 0; i < 4; ++i) {
            const int row0 = bm + wm * 64 + i * 16 + ((lane >> 4) << 2);
            #pragma unroll
            for (int ii = 0; ii < 4; ++ii) {
                const float v = acc[i][j][ii] + bv;
                if constexpr (OUT_BF16)
                    ((unsigned short*)Cv)[(size_t)(row0 + ii) * N + col] = f2bf(v);
                else
                    ((float*)Cv)[(size_t)(row0 + ii) * N + col] = v;
            }
        }
    }
}

// ---------------------------------------------------------------------------
// Depthwise conv1d (k=3) + bias + exact GELU (vectorized weight loads).
// ---------------------------------------------------------------------------
__global__ __launch_bounds__(256) void dwgelu_kernel(const unsigned short* __restrict__ qkv,
                                                     const float* __restrict__ dww,
                                                     const float* __restrict__ dwb,
                                                     unsigned short* __restrict__ g) {
    const int idx = blockIdx.x * 256 + threadIdx.x;
    const int m   = idx >> 7;
    const int c8  = (idx & 127) << 3;
    const int t   = m & (Q_ - 1);
    const unsigned short* row = qkv + (size_t)m * NQKV + c8;

    unsigned short cur[8], prv[8] = {0}, nxt[8] = {0};
    *(uint4*)cur = *(const uint4*)row;
    if (t > 0)      *(uint4*)prv = *(const uint4*)(row - NQKV);
    if (t < Q_ - 1) *(uint4*)nxt = *(const uint4*)(row + NQKV);

    float dwl[24];
    #pragma unroll
    for (int q2 = 0; q2 < 6; ++q2)
        *(f32x4*)&dwl[q2 * 4] = *(const f32x4*)&dww[c8 * 3 + q2 * 4];
    float db[8];
    *(f32x4*)&db[0] = *(const f32x4*)&dwb[c8];
    *(f32x4*)&db[4] = *(const f32x4*)&dwb[c8 + 4];

    unsigned short o[8];
    #pragma unroll
    for (int j = 0; j < 8; ++j) {
        float v = bf2f(prv[j]) * dwl[j * 3 + 0] + bf2f(cur[j]) * dwl[j * 3 + 1]
                + bf2f(nxt[j]) * dwl[j * 3 + 2] + db[j];
        v = 0.5f * v * (1.0f + erff(v * 0.70710678118654752f));
        o[j] = f2bf(v);
    }
    *(uint4*)(g + (size_t)m * D_ + c8) = *(uint4*)o;
}

// ---------------------------------------------------------------------------
// Fused banded-score + softmax + band coefficients + PV, one wave per 16-t
// tile of one (b,h).  pos in [t-8, t+8] so only a 17-wide diagonal band of
// QK^T matters.  PV uses 32 V rows preloaded to registers and the c-band
// kept in LDS (aligned f32x4 broadcast reads).
// ---------------------------------------------------------------------------
__global__ __launch_bounds__(256) void coeff_pv_kernel(const unsigned short* __restrict__ qkv,
                                                       const unsigned short* __restrict__ offb,
                                                       const float* __restrict__ rel_scale_p,
                                                       unsigned short* __restrict__ attb) {
    __shared__ __align__(16) float S[4][16][33];
    __shared__ __align__(16) float C[4][16][32];
    const int tid  = threadIdx.x;
    const int w    = tid >> 6, lane = tid & 63;
    const int tile = blockIdx.x * 4 + w;      // (b,h,t0/16)
    const int t0   = (tile & 127) << 4;
    const int h    = (tile >> 7) & 15;
    const int b    = tile >> 11;
    const int fr   = lane & 15;
    const int fo   = (lane >> 4) << 3;

    // ---- Phase 1: banded QK^T ----
    const unsigned short* qrow = qkv + (size_t)(b * Q_ + t0 + fr) * NQKV + h * DH_ + fo;
    const bf16x8 af0 = *(const bf16x8*)qrow;
    const bf16x8 af1 = *(const bf16x8*)(qrow + 32);

    f32x4 acc0 = (f32x4){0.f, 0.f, 0.f, 0.f};
    f32x4 acc1 = acc0;
    {
        int j = min(max(t0 - 8 + fr, 0), Q_ - 1);
        const unsigned short* krow = qkv + (size_t)(b * Q_ + j) * NQKV + D_ + h * DH_ + fo;
        acc0 = __builtin_amdgcn_mfma_f32_16x16x32_bf16(af0, *(const bf16x8*)krow, acc0, 0, 0, 0);
        acc0 = __builtin_amdgcn_mfma_f32_16x16x32_bf16(af1, *(const bf16x8*)(krow + 32), acc0, 0, 0, 0);
    }
    {
        int j = min(max(t0 + 8 + fr, 0), Q_ - 1);
        const unsigned short* krow = qkv + (size_t)(b * Q_ + j) * NQKV + D_ + h * DH_ + fo;
        acc1 = __builtin_amdgcn_mfma_f32_16x16x32_bf16(af0, *(const bf16x8*)krow, acc1, 0, 0, 0);
        acc1 = __builtin_amdgcn_mfma_f32_16x16x32_bf16(af1, *(const bf16x8*)(krow + 32), acc1, 0, 0, 0);
    }

    // V preload: rows t0-8 .. t0+23 (clamped), lane = dh
    float vj[32];
    {
        const unsigned short* vb = qkv + (size_t)b * Q_ * NQKV + 2 * D_ + h * DH_ + lane;
        #pragma unroll
        for (int i2 = 0; i2 < 32; ++i2) {
            const int j = min(max(t0 - 8 + i2, 0), Q_ - 1);
            vj[i2] = bf2f(vb[(size_t)j * NQKV]);
        }
    }

    // write S band (D layout col=lane&15, row=(lane>>4)*4+reg); zero C
    const int row0 = (lane >> 4) << 2;
    #pragma unroll
    for (int ii = 0; ii < 4; ++ii) {
        S[w][row0 + ii][fr]      = acc0[ii];
        S[w][row0 + ii][16 + fr] = acc1[ii];
    }
    {
        const int tr = lane >> 2, cg = (lane & 3) << 3;
        #pragma unroll
        for (int k = 0; k < 8; ++k) C[w][tr][cg + k] = 0.f;
    }
    __syncthreads();

    // ---- Phase 2: softmax + scatter ----
    const int tloc = lane & 15;
    const int rs   = lane >> 4;
    const int t    = t0 + tloc;
    const float rel_scale = rel_scale_p[0];
    const unsigned short* offrow = offb + (size_t)(b * Q_ + t) * HR_ + h * R_;

    float sc[3], fr3[3];
    int   cl[3], ch[3];
    #pragma unroll
    for (int i = 0; i < 3; ++i) {
        const int r = rs * 3 + i;
        const float off    = bf2f(offrow[r]);
        const float anchor = -2.0f + (4.0f / 11.0f) * (float)r;
        float pos = (float)t + anchor + 6.0f * tanhf(off);
        pos = fminf(fmaxf(pos, 0.0f), (float)(Q_ - 1));
        const float fl = floorf(pos);
        const int lo = (int)fl;
        const int hi = (int)ceilf(pos);
        const float f = pos - fl;
        cl[i] = lo - t0 + 8;
        ch[i] = hi - t0 + 8;
        fr3[i] = f;
        const float slo = S[w][tloc][cl[i]];
        const float shi = S[w][tloc][ch[i]];
        sc[i] = (slo * (1.0f - f) + shi * f) * 0.125f - rel_scale * fabsf(pos - (float)t);
    }

    float mx = fmaxf(fmaxf(sc[0], sc[1]), sc[2]);
    mx = fmaxf(mx, __shfl_xor(mx, 16));
    mx = fmaxf(mx, __shfl_xor(mx, 32));
    float e[3];
    #pragma unroll
    for (int i = 0; i < 3; ++i) e[i] = expf(sc[i] - mx);
    float sum = e[0] + e[1] + e[2];
    sum += __shfl_xor(sum, 16);
    sum += __shfl_xor(sum, 32);
    const float inv = 1.0f / sum;

    #pragma unroll
    for (int i = 0; i < 3; ++i) {
        const float wgt = e[i] * inv;
        atomicAdd(&C[w][tloc][cl[i]], wgt * (1.0f - fr3[i]));
        atomicAdd(&C[w][tloc][ch[i]], wgt * fr3[i]);
    }
    __syncthreads();

    // ---- Phase 3: banded PV, out[t0+tl][dh=lane] ----
    #pragma unroll
    for (int tl = 0; tl < 16; ++tl) {
        const int st = tl & ~3;       // aligned window start (st+19 <= 31)
        float cw[20];
        #pragma unroll
        for (int q2 = 0; q2 < 5; ++q2)
            *(f32x4*)&cw[q2 * 4] = *(const f32x4*)&C[w][tl][st + q2 * 4];
        float acc2 = 0.f;
        #pragma unroll
        for (int k = 0; k <= 16; ++k)
            acc2 = fmaf(cw[tl - st + k], vj[tl + k], acc2);
        attb[(size_t)(b * Q_ + t0 + tl) * D_ + h * DH_ + lane] = f2bf(acc2);
    }
}

// ---------------------------------------------------------------------------
// Launch
// ---------------------------------------------------------------------------
extern "C" void kernel_launch(void* const* d_in, const int* in_sizes, int n_in,
                              void* d_out, int out_size, void* d_ws, size_t ws_size,
                              hipStream_t stream) {
    const float* x    = (const float*)d_in[0];
    const float* wq   = (const float*)d_in[1];
    const float* bq   = (const float*)d_in[2];
    const float* wk   = (const float*)d_in[3];
    const float* bk   = (const float*)d_in[4];
    const float* wv   = (const float*)d_in[5];
    const float* bv   = (const float*)d_in[6];
    const float* wo   = (const float*)d_in[7];
    const float* bo   = (const float*)d_in[8];
    const float* dww  = (const float*)d_in[9];
    const float* dwb  = (const float*)d_in[10];
    const float* pww  = (const float*)d_in[11];
    const float* pwb  = (const float*)d_in[12];
    const float* rsc  = (const float*)d_in[13];
    float* out = (float*)d_out;

    unsigned short* xb   = (unsigned short*)d_ws;              // M_*D_
    unsigned short* wqkv = xb   + (size_t)M_ * D_;             // NQKV*D_
    unsigned short* wob  = wqkv + (size_t)NQKV * D_;           // D_*D_
    unsigned short* pwwb = wob  + (size_t)D_ * D_;             // HR_*D_
    unsigned short* qkv  = pwwb + (size_t)HR_ * D_;            // M_*NQKV
    unsigned short* gb   = qkv  + (size_t)M_ * NQKV;           // M_*D_
    unsigned short* offb = gb   + (size_t)M_ * D_;             // M_*HR_
    unsigned short* attb = offb + (size_t)M_ * HR_;            // M_*D_
    float*          bqkv = (float*)(attb + (size_t)M_ * D_);   // NQKV

    dim3 blk(256);

    // all fp32->bf16 conversions + bias concat in one launch
    hipLaunchKernelGGL(cvt_all, dim3(4204), blk, 0, stream,
                       x, wq, wk, wv, wo, pww, bq, bk, bv, xb, wqkv, wob, pwwb, bqkv);

    // fused QKV projection: (4096 x 1024) @ (3072 x 1024)^T
    hipLaunchKernelGGL((gemm_mfma<128, true>), dim3(NQKV / 128, M_ / 128), blk, 0, stream,
                       xb, wqkv, bqkv, qkv, M_, NQKV, D_);

    // depthwise conv + gelu
    hipLaunchKernelGGL(dwgelu_kernel, dim3(M_ * 128 / 256), blk, 0, stream, qkv, dww, dwb, gb);

    // pointwise conv -> raw offsets
    hipLaunchKernelGGL((gemm_mfma<64, true>), dim3(HR_ / 64, M_ / 128), blk, 0, stream,
                       gb, pwwb, pwb, offb, M_, HR_, D_);

    // banded score + softmax + coefficients + PV (fused)
    hipLaunchKernelGGL(coeff_pv_kernel, dim3(B_ * H_ * (Q_ / 16) / 4), blk, 0, stream,
                       qkv, offb, rsc, attb);

    // output projection -> fp32 d_out
    hipLaunchKernelGGL((gemm_mfma<64, false>), dim3(D_ / 64, M_ / 128), blk, 0, stream,
                       attb, wob, bo, out, M_, D_, D_);
}